// Round 1
// baseline (1357.638 us; speedup 1.0000x reference)
//
#include <hip/hip_runtime.h>

constexpr int BB = 2, HH = 16, LL = 2048, DD = 128;
constexpr int QB = 32;        // q rows per workgroup
constexpr int KB = 64;        // keys per k-tile
constexpr int NKT = LL / KB;  // 32
constexpr float SCALE = 0.08838834764831845f;  // 1/sqrt(128)

typedef __attribute__((ext_vector_type(8))) short bf16x8;
typedef __attribute__((ext_vector_type(8))) unsigned short u16x8;
typedef __attribute__((ext_vector_type(4))) float f32x4;

static __device__ __forceinline__ unsigned short f2bf(float f) {
  unsigned int u = __builtin_bit_cast(unsigned int, f);
  u += 0x7fffu + ((u >> 16) & 1u);   // round-to-nearest-even
  return (unsigned short)(u >> 16);
}
static __device__ __forceinline__ float bf2f(unsigned short h) {
  return __builtin_bit_cast(float, (unsigned int)h << 16);
}

__global__ __launch_bounds__(512, 2)
void Attention_22849226014998_kernel(
    const float* __restrict__ q, const float* __restrict__ k,
    const float* __restrict__ v, const int* __restrict__ mask,
    const float* __restrict__ probs, const float* __restrict__ alphap,
    float* __restrict__ outA, float* __restrict__ outP)
{
  __shared__ unsigned short sQ[QB * DD];   // 8 KB, bf16, swizzled
  __shared__ unsigned short sKV[KB * DD];  // 16 KB, K tile (ph1) / Vt (ph2)
  __shared__ unsigned short sE[QB * LL];   // 128 KB, unnormalized exp(S), bf16
  __shared__ float sPart[QB * 16];
  __shared__ float sInv[QB];

  const int tid = threadIdx.x;
  const int lane = tid & 63;
  const int wid = tid >> 6;
  const int l15 = lane & 15;
  const int l4 = lane >> 4;
  const int bid = blockIdx.x;
  const int bh = bid >> 6;   // / (L/QB) = 64
  const int qt = bid & 63;
  const int b = bh >> 4;     // / H
  const int q0 = qt * QB;

  const float alpha = alphap[0];
  const float* qg = q + (size_t)(bh * LL + q0) * DD;
  const float* kg = k + (size_t)bh * LL * DD;
  const float* vg = v + (size_t)bh * LL * DD;
  const float* pg = probs + (size_t)b * LL * LL + (size_t)q0 * LL;
  const int* mg = mask + (size_t)b * LL * LL + (size_t)q0 * LL;
  float* oA = outA + (size_t)(bh * LL + q0) * DD;
  float* oP = outP + (size_t)bh * LL * LL + (size_t)q0 * LL;

  // ---- load Q tile -> LDS bf16 (XOR-swizzled rows) ----
  {
    int row = tid >> 4;
    int d0 = (tid & 15) * 8;
    const float* src = qg + row * DD + d0;
    float4 x0 = *(const float4*)(src);
    float4 x1 = *(const float4*)(src + 4);
    u16x8 t;
    t[0] = f2bf(x0.x); t[1] = f2bf(x0.y); t[2] = f2bf(x0.z); t[3] = f2bf(x0.w);
    t[4] = f2bf(x1.x); t[5] = f2bf(x1.y); t[6] = f2bf(x1.z); t[7] = f2bf(x1.w);
    *(u16x8*)(&sQ[row * DD + (d0 ^ ((row & 7) << 3))]) = t;
  }

  const int wr = wid >> 2;  // 0..1 : q-row group
  const int wc = wid & 3;   // 0..3 : key-col group (phase 1)

  // ---- phase 1: e = exp(scale*QK^T + probs*alpha), masked->0, into sE ----
  for (int kt = 0; kt < NKT; ++kt) {
    __syncthreads();
    {
      int key = tid >> 3;
      int d0 = (tid & 7) * 16;
      const float* src = kg + (size_t)(kt * KB + key) * DD + d0;
      float4 x0 = *(const float4*)(src);
      float4 x1 = *(const float4*)(src + 4);
      float4 x2 = *(const float4*)(src + 8);
      float4 x3 = *(const float4*)(src + 12);
      u16x8 t0, t1;
      t0[0] = f2bf(x0.x); t0[1] = f2bf(x0.y); t0[2] = f2bf(x0.z); t0[3] = f2bf(x0.w);
      t0[4] = f2bf(x1.x); t0[5] = f2bf(x1.y); t0[6] = f2bf(x1.z); t0[7] = f2bf(x1.w);
      t1[0] = f2bf(x2.x); t1[1] = f2bf(x2.y); t1[2] = f2bf(x2.z); t1[3] = f2bf(x2.w);
      t1[4] = f2bf(x3.x); t1[5] = f2bf(x3.y); t1[6] = f2bf(x3.z); t1[7] = f2bf(x3.w);
      int sw = (key & 7) << 3;
      *(u16x8*)(&sKV[key * DD + (d0 ^ sw)]) = t0;
      *(u16x8*)(&sKV[key * DD + ((d0 + 8) ^ sw)]) = t1;
    }
    __syncthreads();

    f32x4 acc = {0.f, 0.f, 0.f, 0.f};
    int qrow = wr * 16 + l15;
    int krow = wc * 16 + l15;
    #pragma unroll
    for (int kc = 0; kc < 4; ++kc) {
      int dcol = kc * 32 + l4 * 8;
      bf16x8 aQ = *(const bf16x8*)(&sQ[qrow * DD + (dcol ^ ((qrow & 7) << 3))]);
      bf16x8 bK = *(const bf16x8*)(&sKV[krow * DD + (dcol ^ ((krow & 7) << 3))]);
      acc = __builtin_amdgcn_mfma_f32_16x16x32_bf16(aQ, bK, acc, 0, 0, 0);
    }
    int keyl = kt * KB + wc * 16 + l15;
    #pragma unroll
    for (int r = 0; r < 4; ++r) {
      int rowl = wr * 16 + l4 * 4 + r;
      float s = acc[r] * SCALE + pg[(size_t)rowl * LL + keyl] * alpha;
      int m = mg[(size_t)rowl * LL + keyl];
      float e = m ? __expf(s) : 0.f;   // no max-subtraction: |s| small, fp32 safe
      sE[rowl * LL + (keyl ^ ((rowl & 7) << 3))] = f2bf(e);
    }
  }
  __syncthreads();

  // ---- rowsums -> sInv ----
  {
    int row = tid & 31;
    int cb = tid >> 5;
    float sum = 0.f;
    #pragma unroll
    for (int i = 0; i < 16; ++i) {
      int key = cb * 128 + i * 8;
      u16x8 e8 = *(const u16x8*)(&sE[row * LL + (key ^ ((row & 7) << 3))]);
      #pragma unroll
      for (int j = 0; j < 8; ++j) sum += bf2f(e8[j]);
    }
    sPart[row * 16 + cb] = sum;
  }
  __syncthreads();
  if (tid < 32) {
    float s = 0.f;
    #pragma unroll
    for (int i = 0; i < 16; ++i) s += sPart[tid * 16 + i];
    sInv[tid] = 1.0f / s;
  }
  __syncthreads();

  // ---- write attn_p = e * inv (fp32, coalesced float4) ----
  for (int i = 0; i < 16; ++i) {
    int flat = i * 4096 + tid * 8;
    int row = flat >> 11;
    int key = flat & 2047;
    float inv = sInv[row];
    u16x8 e8 = *(const u16x8*)(&sE[row * LL + (key ^ ((row & 7) << 3))]);
    float4 o0, o1;
    o0.x = bf2f(e8[0]) * inv; o0.y = bf2f(e8[1]) * inv;
    o0.z = bf2f(e8[2]) * inv; o0.w = bf2f(e8[3]) * inv;
    o1.x = bf2f(e8[4]) * inv; o1.y = bf2f(e8[5]) * inv;
    o1.z = bf2f(e8[6]) * inv; o1.w = bf2f(e8[7]) * inv;
    float* dst = oP + (size_t)row * LL + key;
    *(float4*)(dst) = o0;
    *(float4*)(dst + 4) = o1;
  }

  // ---- phase 2: O = (sum_k e * V) * inv ; V staged transposed in LDS ----
  const int wd = wid & 3;   // 0..3 : d-col group
  f32x4 accO0 = {0.f, 0.f, 0.f, 0.f};
  f32x4 accO1 = {0.f, 0.f, 0.f, 0.f};
  for (int kt = 0; kt < NKT; ++kt) {
    __syncthreads();
    {
      int key = tid >> 3;
      int d0 = (tid & 7) * 16;
      const float* src = vg + (size_t)(kt * KB + key) * DD + d0;
      float4 x0 = *(const float4*)(src);
      float4 x1 = *(const float4*)(src + 4);
      float4 x2 = *(const float4*)(src + 8);
      float4 x3 = *(const float4*)(src + 12);
      float f[16] = {x0.x, x0.y, x0.z, x0.w, x1.x, x1.y, x1.z, x1.w,
                     x2.x, x2.y, x2.z, x2.w, x3.x, x3.y, x3.z, x3.w};
      #pragma unroll
      for (int i = 0; i < 16; ++i) {
        int d = d0 + i;
        sKV[d * KB + (key ^ ((d & 7) << 3))] = f2bf(f[i]);  // Vt[d][key]
      }
    }
    __syncthreads();

    int rowA = wr * 16 + l15;
    #pragma unroll
    for (int kk = 0; kk < 2; ++kk) {
      int kb = kk * 32 + l4 * 8;
      int gk = kt * KB + kb;
      bf16x8 aP = *(const bf16x8*)(&sE[rowA * LL + (gk ^ ((rowA & 7) << 3))]);
      {
        int dcol = wd * 32 + l15;
        bf16x8 bV = *(const bf16x8*)(&sKV[dcol * KB + (kb ^ ((dcol & 7) << 3))]);
        accO0 = __builtin_amdgcn_mfma_f32_16x16x32_bf16(aP, bV, accO0, 0, 0, 0);
      }
      {
        int dcol = wd * 32 + 16 + l15;
        bf16x8 bV = *(const bf16x8*)(&sKV[dcol * KB + (kb ^ ((dcol & 7) << 3))]);
        accO1 = __builtin_amdgcn_mfma_f32_16x16x32_bf16(aP, bV, accO1, 0, 0, 0);
      }
    }
  }

  // ---- epilogue: normalize + store attention ----
  #pragma unroll
  for (int r = 0; r < 4; ++r) {
    int rowl = wr * 16 + l4 * 4 + r;
    float inv = sInv[rowl];
    oA[(size_t)rowl * DD + wd * 32 + l15] = accO0[r] * inv;
    oA[(size_t)rowl * DD + wd * 32 + 16 + l15] = accO1[r] * inv;
  }
}

extern "C" void kernel_launch(void* const* d_in, const int* in_sizes, int n_in,
                              void* d_out, int out_size, void* d_ws, size_t ws_size,
                              hipStream_t stream) {
  const float* q = (const float*)d_in[0];
  const float* k = (const float*)d_in[1];
  const float* v = (const float*)d_in[2];
  const int* mask = (const int*)d_in[3];
  const float* probs = (const float*)d_in[4];
  const float* alpha = (const float*)d_in[5];
  float* outA = (float*)d_out;
  float* outP = outA + (size_t)BB * HH * LL * DD;
  dim3 grid(BB * HH * (LL / QB));
  dim3 block(512);
  hipLaunchKernelGGL(Attention_22849226014998_kernel, grid, block, 0, stream,
                     q, k, v, mask, probs, alpha, outA, outP);
}

// Round 2
// 465.429 us; speedup vs baseline: 2.9170x; 2.9170x over previous
//
#include <hip/hip_runtime.h>

constexpr int BB = 2, HH = 16, LL = 2048, DD = 128;
constexpr int QB = 64;        // q rows per workgroup
constexpr int KB = 32;        // keys per tile
constexpr int NKT = LL / KB;  // 64
constexpr float SCALE = 0.08838834764831845f;  // 1/sqrt(128)

typedef __attribute__((ext_vector_type(8))) short bf16x8;
typedef __attribute__((ext_vector_type(8))) unsigned short u16x8;
typedef __attribute__((ext_vector_type(4))) float f32x4;

static __device__ __forceinline__ unsigned short f2bf(float f) {
  unsigned int u = __builtin_bit_cast(unsigned int, f);
  u += 0x7fffu + ((u >> 16) & 1u);   // round-to-nearest-even
  return (unsigned short)(u >> 16);
}
// swizzle slot for 32-element (64 B) rows: varies with BOTH d-bits 1-2 (read
// lanes: consecutive rows) and d-bits 3-4 (write lanes: rows stride 8)
static __device__ __forceinline__ int slotRC(int r) { return ((r >> 1) ^ (r >> 3)) & 3; }

__global__ __launch_bounds__(512, 4)
void Attention_22849226014998_kernel(
    const float* __restrict__ q, const float* __restrict__ k,
    const float* __restrict__ v, const int* __restrict__ mask,
    const float* __restrict__ probs, const float* __restrict__ alphap,
    float* __restrict__ outA, float* __restrict__ outP)
{
  __shared__ unsigned short sQ[QB * DD];        // 16 KB
  __shared__ unsigned short sK[2][KB * DD];     // 16 KB (dbuf)
  __shared__ unsigned short sVt[2][DD * KB];    // 16 KB (dbuf, transposed)
  __shared__ unsigned short sP[QB * KB];        // 4 KB
  __shared__ float sRed[QB * 2];
  __shared__ float sInv[QB];

  const int tid = threadIdx.x;
  const int lane = tid & 63;
  const int wid = tid >> 6;
  const int l15 = lane & 15;
  const int l4 = lane >> 4;
  const int wr = wid >> 1;   // 0..3 : q-row group (16 rows each)
  const int wc = wid & 1;    // 0..1 : key group (ph1) / d-half (ph2)

  const int bid = blockIdx.x;
  const int qt = bid >> 5;   // 0..31
  const int bh = bid & 31;   // 0..31  (consecutive WGs share probs/mask rows)
  const int b = bh >> 4;
  const int q0 = qt * QB;

  const float alpha = alphap[0];
  const float* qg = q + (size_t)(bh * LL + q0) * DD;
  const float* kg = k + (size_t)bh * LL * DD;
  const float* vg = v + (size_t)bh * LL * DD;
  const float* pg = probs + (size_t)b * LL * LL + (size_t)q0 * LL;
  const int* mg = mask + (size_t)b * LL * LL + (size_t)q0 * LL;
  float* oA = outA + (size_t)(bh * LL + q0) * DD;
  float* oP = outP + (size_t)bh * LL * LL + (size_t)q0 * LL;

  // ---- Q -> LDS (bf16, row-swizzled) ----
  {
    int row = tid >> 3;
    int d0 = (tid & 7) * 16;
    const float* src = qg + row * DD + d0;
    float4 x0 = *(const float4*)(src);
    float4 x1 = *(const float4*)(src + 4);
    float4 x2 = *(const float4*)(src + 8);
    float4 x3 = *(const float4*)(src + 12);
    u16x8 t0, t1;
    t0[0] = f2bf(x0.x); t0[1] = f2bf(x0.y); t0[2] = f2bf(x0.z); t0[3] = f2bf(x0.w);
    t0[4] = f2bf(x1.x); t0[5] = f2bf(x1.y); t0[6] = f2bf(x1.z); t0[7] = f2bf(x1.w);
    t1[0] = f2bf(x2.x); t1[1] = f2bf(x2.y); t1[2] = f2bf(x2.z); t1[3] = f2bf(x2.w);
    t1[4] = f2bf(x3.x); t1[5] = f2bf(x3.y); t1[6] = f2bf(x3.z); t1[7] = f2bf(x3.w);
    int sw = (row & 7) << 3;
    *(u16x8*)(&sQ[row * DD + (d0 ^ sw)]) = t0;
    *(u16x8*)(&sQ[row * DD + ((d0 + 8) ^ sw)]) = t1;
  }

  const int krow = tid >> 4;         // 0..31 (K & V staging row)
  const int kcol = (tid & 15) * 8;   // 0..120
  const int keyloc = wc * 16 + l15;  // 0..31
  const int row0 = wr * 16 + l4 * 4; // wave's acc row base

  // =================== PASS A: rowsums ===================
  float4 kA, kB;
  {
    const float* src = kg + (size_t)krow * DD + kcol;
    kA = *(const float4*)(src);
    kB = *(const float4*)(src + 4);
  }
  float sum0 = 0.f, sum1 = 0.f, sum2 = 0.f, sum3 = 0.f;
  int cur = 0;
  for (int kt = 0; kt < NKT; ++kt) {
    int keyg = kt * KB + keyloc;
    const float* pgr = pg + keyg;
    const int* mgr = mg + keyg;
    float p0 = pgr[(size_t)(row0 + 0) * LL];
    float p1 = pgr[(size_t)(row0 + 1) * LL];
    float p2 = pgr[(size_t)(row0 + 2) * LL];
    float p3 = pgr[(size_t)(row0 + 3) * LL];
    int m0 = mgr[(size_t)(row0 + 0) * LL];
    int m1 = mgr[(size_t)(row0 + 1) * LL];
    int m2 = mgr[(size_t)(row0 + 2) * LL];
    int m3 = mgr[(size_t)(row0 + 3) * LL];
    {
      u16x8 t;
      t[0] = f2bf(kA.x); t[1] = f2bf(kA.y); t[2] = f2bf(kA.z); t[3] = f2bf(kA.w);
      t[4] = f2bf(kB.x); t[5] = f2bf(kB.y); t[6] = f2bf(kB.z); t[7] = f2bf(kB.w);
      *(u16x8*)(&sK[cur][krow * DD + (kcol ^ ((krow & 7) << 3))]) = t;
    }
    if (kt + 1 < NKT) {
      const float* src = kg + (size_t)((kt + 1) * KB + krow) * DD + kcol;
      kA = *(const float4*)(src);
      kB = *(const float4*)(src + 4);
    }
    __syncthreads();
    f32x4 acc = {0.f, 0.f, 0.f, 0.f};
    const int qrow = wr * 16 + l15;
    #pragma unroll
    for (int kc = 0; kc < 4; ++kc) {
      int col = kc * 32 + l4 * 8;
      bf16x8 aQ = *(const bf16x8*)(&sQ[qrow * DD + (col ^ ((qrow & 7) << 3))]);
      bf16x8 bK = *(const bf16x8*)(&sK[cur][keyloc * DD + (col ^ ((keyloc & 7) << 3))]);
      acc = __builtin_amdgcn_mfma_f32_16x16x32_bf16(aQ, bK, acc, 0, 0, 0);
    }
    sum0 += m0 ? __expf(acc[0] * SCALE + p0 * alpha) : 0.f;
    sum1 += m1 ? __expf(acc[1] * SCALE + p1 * alpha) : 0.f;
    sum2 += m2 ? __expf(acc[2] * SCALE + p2 * alpha) : 0.f;
    sum3 += m3 ? __expf(acc[3] * SCALE + p3 * alpha) : 0.f;
    cur ^= 1;
  }

  // reduce over the 16 lanes of each row group (xor masks stay in-group)
  #pragma unroll
  for (int m = 1; m < 16; m <<= 1) {
    sum0 += __shfl_xor(sum0, m, 64);
    sum1 += __shfl_xor(sum1, m, 64);
    sum2 += __shfl_xor(sum2, m, 64);
    sum3 += __shfl_xor(sum3, m, 64);
  }
  if (l15 == 0) {
    sRed[(row0 + 0) * 2 + wc] = sum0;
    sRed[(row0 + 1) * 2 + wc] = sum1;
    sRed[(row0 + 2) * 2 + wc] = sum2;
    sRed[(row0 + 3) * 2 + wc] = sum3;
  }
  __syncthreads();
  if (tid < QB) sInv[tid] = 1.0f / (sRed[tid * 2] + sRed[tid * 2 + 1]);
  __syncthreads();

  // =================== PASS B: attn_p + O ===================
  float4 vA, vB;
  {
    const float* src = kg + (size_t)krow * DD + kcol;
    kA = *(const float4*)(src);
    kB = *(const float4*)(src + 4);
    const float* vsrc = vg + (size_t)krow * DD + kcol;
    vA = *(const float4*)(vsrc);
    vB = *(const float4*)(vsrc + 4);
  }
  f32x4 o0 = {0.f,0.f,0.f,0.f}, o1 = {0.f,0.f,0.f,0.f};
  f32x4 o2 = {0.f,0.f,0.f,0.f}, o3 = {0.f,0.f,0.f,0.f};
  cur = 0;
  for (int kt = 0; kt < NKT; ++kt) {
    int keyg = kt * KB + keyloc;
    const float* pgr = pg + keyg;
    const int* mgr = mg + keyg;
    float p0 = pgr[(size_t)(row0 + 0) * LL];
    float p1 = pgr[(size_t)(row0 + 1) * LL];
    float p2 = pgr[(size_t)(row0 + 2) * LL];
    float p3 = pgr[(size_t)(row0 + 3) * LL];
    int m0 = mgr[(size_t)(row0 + 0) * LL];
    int m1 = mgr[(size_t)(row0 + 1) * LL];
    int m2 = mgr[(size_t)(row0 + 2) * LL];
    int m3 = mgr[(size_t)(row0 + 3) * LL];
    {
      u16x8 t;
      t[0] = f2bf(kA.x); t[1] = f2bf(kA.y); t[2] = f2bf(kA.z); t[3] = f2bf(kA.w);
      t[4] = f2bf(kB.x); t[5] = f2bf(kB.y); t[6] = f2bf(kB.z); t[7] = f2bf(kB.w);
      *(u16x8*)(&sK[cur][krow * DD + (kcol ^ ((krow & 7) << 3))]) = t;
    }
    {
      // transposed V: sVt[d][key], scalar stores, conflict-broken by slotRC
      #define VST(i, val) { int d = kcol + (i); \
        sVt[cur][d * KB + (krow ^ (slotRC(d) << 3))] = f2bf(val); }
      VST(0, vA.x) VST(1, vA.y) VST(2, vA.z) VST(3, vA.w)
      VST(4, vB.x) VST(5, vB.y) VST(6, vB.z) VST(7, vB.w)
      #undef VST
    }
    if (kt + 1 < NKT) {
      const float* src = kg + (size_t)((kt + 1) * KB + krow) * DD + kcol;
      kA = *(const float4*)(src);
      kB = *(const float4*)(src + 4);
      const float* vsrc = vg + (size_t)((kt + 1) * KB + krow) * DD + kcol;
      vA = *(const float4*)(vsrc);
      vB = *(const float4*)(vsrc + 4);
    }
    __syncthreads();   // B1: staged tiles visible

    f32x4 acc = {0.f, 0.f, 0.f, 0.f};
    const int qrow = wr * 16 + l15;
    #pragma unroll
    for (int kc = 0; kc < 4; ++kc) {
      int col = kc * 32 + l4 * 8;
      bf16x8 aQ = *(const bf16x8*)(&sQ[qrow * DD + (col ^ ((qrow & 7) << 3))]);
      bf16x8 bK = *(const bf16x8*)(&sK[cur][keyloc * DD + (col ^ ((keyloc & 7) << 3))]);
      acc = __builtin_amdgcn_mfma_f32_16x16x32_bf16(aQ, bK, acc, 0, 0, 0);
    }
    {
      #define EPI(r, pr, mr) { int rowl = row0 + (r); \
        float e = (mr) ? __expf(acc[r] * SCALE + (pr) * alpha) : 0.f; \
        float pn = e * sInv[rowl]; \
        oP[(size_t)rowl * LL + keyg] = pn; \
        sP[rowl * KB + (keyloc ^ (slotRC(rowl) << 3))] = f2bf(pn); }
      EPI(0, p0, m0) EPI(1, p1, m1) EPI(2, p2, m2) EPI(3, p3, m3)
      #undef EPI
    }
    __syncthreads();   // B2: sP visible

    const int prow = wr * 16 + l15;
    bf16x8 aP = *(const bf16x8*)(&sP[prow * KB + ((l4 * 8) ^ (slotRC(prow) << 3))]);
    {
      int dcol = wc * 64 + l15;
      bf16x8 bV = *(const bf16x8*)(&sVt[cur][dcol * KB + ((l4 * 8) ^ (slotRC(dcol) << 3))]);
      o0 = __builtin_amdgcn_mfma_f32_16x16x32_bf16(aP, bV, o0, 0, 0, 0);
    }
    {
      int dcol = wc * 64 + 16 + l15;
      bf16x8 bV = *(const bf16x8*)(&sVt[cur][dcol * KB + ((l4 * 8) ^ (slotRC(dcol) << 3))]);
      o1 = __builtin_amdgcn_mfma_f32_16x16x32_bf16(aP, bV, o1, 0, 0, 0);
    }
    {
      int dcol = wc * 64 + 32 + l15;
      bf16x8 bV = *(const bf16x8*)(&sVt[cur][dcol * KB + ((l4 * 8) ^ (slotRC(dcol) << 3))]);
      o2 = __builtin_amdgcn_mfma_f32_16x16x32_bf16(aP, bV, o2, 0, 0, 0);
    }
    {
      int dcol = wc * 64 + 48 + l15;
      bf16x8 bV = *(const bf16x8*)(&sVt[cur][dcol * KB + ((l4 * 8) ^ (slotRC(dcol) << 3))]);
      o3 = __builtin_amdgcn_mfma_f32_16x16x32_bf16(aP, bV, o3, 0, 0, 0);
    }
    cur ^= 1;
  }

  // ---- store attention ----
  #pragma unroll
  for (int r = 0; r < 4; ++r) {
    float* dst = oA + (size_t)(row0 + r) * DD + wc * 64 + l15;
    dst[0]  = o0[r];
    dst[16] = o1[r];
    dst[32] = o2[r];
    dst[48] = o3[r];
  }
}

extern "C" void kernel_launch(void* const* d_in, const int* in_sizes, int n_in,
                              void* d_out, int out_size, void* d_ws, size_t ws_size,
                              hipStream_t stream) {
  const float* q = (const float*)d_in[0];
  const float* k = (const float*)d_in[1];
  const float* v = (const float*)d_in[2];
  const int* mask = (const int*)d_in[3];
  const float* probs = (const float*)d_in[4];
  const float* alpha = (const float*)d_in[5];
  float* outA = (float*)d_out;
  float* outP = outA + (size_t)BB * HH * LL * DD;
  dim3 grid(BB * HH * (LL / QB));
  dim3 block(512);
  hipLaunchKernelGGL(Attention_22849226014998_kernel, grid, block, 0, stream,
                     q, k, v, mask, probs, alpha, outA, outP);
}

// Round 3
// 439.014 us; speedup vs baseline: 3.0925x; 1.0602x over previous
//
#include <hip/hip_runtime.h>

constexpr int BB = 2, HH = 16, LL = 2048, DD = 128;
constexpr int QB = 64, KB = 32, NKT = LL / KB;
constexpr float SCALE = 0.08838834764831845f;  // 1/sqrt(128)

typedef __attribute__((ext_vector_type(8))) short bf16x8;
typedef __attribute__((ext_vector_type(8))) unsigned short u16x8;
typedef __attribute__((ext_vector_type(4))) float f32x4;

static __device__ __forceinline__ unsigned short f2bf(float f) {
  unsigned int u = __builtin_bit_cast(unsigned int, f);
  u += 0x7fffu + ((u >> 16) & 1u);   // RNE
  return (unsigned short)(u >> 16);
}
static __device__ __forceinline__ int slotRC(int r) { return ((r >> 1) ^ (r >> 3)) & 3; }

#define GLD16(gsrc, ldst) __builtin_amdgcn_global_load_lds( \
    (const __attribute__((address_space(1))) void*)(gsrc), \
    (__attribute__((address_space(3))) void*)(ldst), 16, 0, 0)

// ---------- prep: K->bf16, V->bf16 transposed [bh][d][k], cpm = mask? probs*alpha : -1e30 ----------
__global__ __launch_bounds__(256)
void prep_kernel(const float* __restrict__ k, const float* __restrict__ v,
                 const int* __restrict__ mask, const float* __restrict__ probs,
                 const float* __restrict__ alphap,
                 unsigned short* __restrict__ kb, unsigned short* __restrict__ vt,
                 float* __restrict__ cpm)
{
  __shared__ unsigned short sT[128 * 72];   // padded transpose tile
  const int bid = blockIdx.x;
  const int bh = bid >> 5, kt = bid & 31;   // 64 keys per kt
  const int t = threadIdx.x;
  const float alpha = alphap[0];
  const float* kg = k + ((size_t)bh * LL + kt * 64) * DD;
  const float* vg = v + ((size_t)bh * LL + kt * 64) * DD;
  unsigned short* kbg = kb + ((size_t)bh * LL + kt * 64) * DD;
  #pragma unroll
  for (int i = 0; i < 8; ++i) {
    int idx = i * 256 + t;
    float4 x = ((const float4*)kg)[idx];
    ushort4 o; o.x = f2bf(x.x); o.y = f2bf(x.y); o.z = f2bf(x.z); o.w = f2bf(x.w);
    ((ushort4*)kbg)[idx] = o;
  }
  #pragma unroll
  for (int i = 0; i < 8; ++i) {
    int idx = i * 256 + t;
    int kr = idx >> 5;
    int d0 = (idx & 31) * 4;
    float4 x = ((const float4*)vg)[idx];
    sT[(d0 + 0) * 72 + kr] = f2bf(x.x);
    sT[(d0 + 1) * 72 + kr] = f2bf(x.y);
    sT[(d0 + 2) * 72 + kr] = f2bf(x.z);
    sT[(d0 + 3) * 72 + kr] = f2bf(x.w);
  }
  {
    const float4* ps = (const float4*)probs;
    const int4* ms = (const int4*)mask;
    float4* cs = (float4*)cpm;
    size_t base = (size_t)bid * 2048;
    #pragma unroll
    for (int i = 0; i < 8; ++i) {
      size_t idx = base + i * 256 + t;
      float4 p = ps[idx];
      int4 m = ms[idx];
      float4 o;
      o.x = m.x ? p.x * alpha : -1e30f;
      o.y = m.y ? p.y * alpha : -1e30f;
      o.z = m.z ? p.z * alpha : -1e30f;
      o.w = m.w ? p.w * alpha : -1e30f;
      cs[idx] = o;
    }
  }
  __syncthreads();
  const int d = t >> 1, h2 = t & 1;
  unsigned short* dst = vt + ((size_t)bh * DD + d) * LL + kt * 64 + h2 * 32;
  const unsigned short* srow = &sT[d * 72 + h2 * 32];
  *(u16x8*)(dst + 0)  = *(const u16x8*)(srow + 0);
  *(u16x8*)(dst + 8)  = *(const u16x8*)(srow + 8);
  *(u16x8*)(dst + 16) = *(const u16x8*)(srow + 16);
  *(u16x8*)(dst + 24) = *(const u16x8*)(srow + 24);
}

// ---------- main fused attention ----------
__global__ __launch_bounds__(512, 6)
void attn_kernel(const float* __restrict__ q, const unsigned short* __restrict__ kb,
                 const unsigned short* __restrict__ vt, const float* __restrict__ cpm,
                 float* __restrict__ outA, float* __restrict__ outP)
{
  __shared__ unsigned short sK[2][KB * DD];   // 16 KB dbuf (DMA-linear, src-swizzled)
  __shared__ unsigned short sVt[2][DD * KB];  // 16 KB dbuf (transposed V)
  __shared__ float sCP[2][QB * KB];           // 16 KB dbuf (probs*alpha+mask tile)
  __shared__ unsigned short sP[QB * KB];      // 4 KB (P tile; aliases sRed/sInv early)
  float* sRed = (float*)sP;
  float* sInv = ((float*)sP) + 128;

  const int tid = threadIdx.x;
  const int lane = tid & 63;
  const int wid = tid >> 6;
  const int l15 = lane & 15;
  const int l4 = lane >> 4;
  const int wr = wid >> 1, wc = wid & 1;

  const int bid = blockIdx.x;
  const int qt = bid >> 5;
  const int bh = bid & 31;     // consecutive WGs share cpm rows (L2/L3 reuse)
  const int b = bh >> 4;
  const int q0 = qt * QB;

  const float* qg = q + (size_t)(bh * LL + q0) * DD;
  const unsigned short* kbh = kb + (size_t)bh * LL * DD;
  const unsigned short* vbh = vt + (size_t)bh * DD * LL;
  const float* cg = cpm + (size_t)b * LL * LL + (size_t)q0 * LL;
  float* oA = outA + (size_t)(bh * LL + q0) * DD;
  float* oP = outP + (size_t)bh * LL * LL + (size_t)q0 * LL;

  // ---- Q -> LDS (staged in sK) -> registers ----
  unsigned short* sKf = &sK[0][0];
  {
    int row = tid >> 3;
    int d0 = (tid & 7) * 16;
    const float* src = qg + row * DD + d0;
    float4 x0 = *(const float4*)(src);
    float4 x1 = *(const float4*)(src + 4);
    float4 x2 = *(const float4*)(src + 8);
    float4 x3 = *(const float4*)(src + 12);
    u16x8 t0, t1;
    t0[0]=f2bf(x0.x); t0[1]=f2bf(x0.y); t0[2]=f2bf(x0.z); t0[3]=f2bf(x0.w);
    t0[4]=f2bf(x1.x); t0[5]=f2bf(x1.y); t0[6]=f2bf(x1.z); t0[7]=f2bf(x1.w);
    t1[0]=f2bf(x2.x); t1[1]=f2bf(x2.y); t1[2]=f2bf(x2.z); t1[3]=f2bf(x2.w);
    t1[4]=f2bf(x3.x); t1[5]=f2bf(x3.y); t1[6]=f2bf(x3.z); t1[7]=f2bf(x3.w);
    int sw = (row & 7) << 3;
    *(u16x8*)(&sKf[row * DD + (d0 ^ sw)]) = t0;
    *(u16x8*)(&sKf[row * DD + ((d0 + 8) ^ sw)]) = t1;
  }
  __syncthreads();
  const int qrow = wr * 16 + l15;
  const int qsw = (qrow & 7) << 3;
  bf16x8 qf0 = *(const bf16x8*)&sKf[qrow * DD + ((  0 + l4 * 8) ^ qsw)];
  bf16x8 qf1 = *(const bf16x8*)&sKf[qrow * DD + (( 32 + l4 * 8) ^ qsw)];
  bf16x8 qf2 = *(const bf16x8*)&sKf[qrow * DD + (( 64 + l4 * 8) ^ qsw)];
  bf16x8 qf3 = *(const bf16x8*)&sKf[qrow * DD + (( 96 + l4 * 8) ^ qsw)];
  __syncthreads();   // Q frags read; sK can be reused for K tiles

  // ---- DMA per-lane source offsets (source pre-swizzled, LDS linear) ----
  const int rK = (wid << 2) + (lane >> 4);                               // 0..31
  const size_t goffK = (size_t)rK * DD + (((lane & 15) ^ (rK & 7)) << 3);
  const int rV = (wid << 4) + (lane >> 2);                               // 0..127
  const size_t goffV = (size_t)rV * LL + (((lane & 3) ^ slotRC(rV)) << 3);
  const int rC = (wid << 3) + (lane >> 3);                               // 0..63
  const size_t goffC = (size_t)rC * LL + (((lane & 7) ^ ((rC >> 2) & 7)) << 2);
  const int ldsOff = wid << 9;   // 1 KB per wave (u16 elements)

  #define DMA_K(BUF, KT) GLD16(kbh + (size_t)(KT) * KB * DD + goffK, &sK[BUF][ldsOff])
  #define DMA_V(BUF, KT) GLD16(vbh + (size_t)(KT) * KB + goffV, &sVt[BUF][ldsOff])
  #define DMA_C(BUF, KT) GLD16(cg + (size_t)(KT) * KB + goffC, &sCP[BUF][wid << 8])

  const int keyloc = wc * 16 + l15;
  const int row0 = wr * 16 + l4 * 4;
  const int ksw = (keyloc & 7) << 3;
  #define CPIDX(R, KEY) ((R) * 32 + (((((KEY) >> 2) ^ (((R) >> 2) & 7)) << 2) | ((KEY) & 3)))

  // =================== PASS A: rowsums ===================
  DMA_K(0, 0);
  DMA_C(0, 0);
  __syncthreads();
  float sum0 = 0.f, sum1 = 0.f, sum2 = 0.f, sum3 = 0.f;
  for (int kt = 0; kt < NKT; ++kt) {
    const int cur = kt & 1;
    if (kt + 1 < NKT) { DMA_K(cur ^ 1, kt + 1); DMA_C(cur ^ 1, kt + 1); }
    f32x4 acc = {0.f, 0.f, 0.f, 0.f};
    bf16x8 bK;
    bK = *(const bf16x8*)&sK[cur][keyloc * DD + ((  0 + l4 * 8) ^ ksw)];
    acc = __builtin_amdgcn_mfma_f32_16x16x32_bf16(qf0, bK, acc, 0, 0, 0);
    bK = *(const bf16x8*)&sK[cur][keyloc * DD + (( 32 + l4 * 8) ^ ksw)];
    acc = __builtin_amdgcn_mfma_f32_16x16x32_bf16(qf1, bK, acc, 0, 0, 0);
    bK = *(const bf16x8*)&sK[cur][keyloc * DD + (( 64 + l4 * 8) ^ ksw)];
    acc = __builtin_amdgcn_mfma_f32_16x16x32_bf16(qf2, bK, acc, 0, 0, 0);
    bK = *(const bf16x8*)&sK[cur][keyloc * DD + (( 96 + l4 * 8) ^ ksw)];
    acc = __builtin_amdgcn_mfma_f32_16x16x32_bf16(qf3, bK, acc, 0, 0, 0);
    sum0 += __expf(acc[0] * SCALE + sCP[cur][CPIDX(row0 + 0, keyloc)]);
    sum1 += __expf(acc[1] * SCALE + sCP[cur][CPIDX(row0 + 1, keyloc)]);
    sum2 += __expf(acc[2] * SCALE + sCP[cur][CPIDX(row0 + 2, keyloc)]);
    sum3 += __expf(acc[3] * SCALE + sCP[cur][CPIDX(row0 + 3, keyloc)]);
    __syncthreads();
  }

  #pragma unroll
  for (int m = 1; m < 16; m <<= 1) {
    sum0 += __shfl_xor(sum0, m, 64);
    sum1 += __shfl_xor(sum1, m, 64);
    sum2 += __shfl_xor(sum2, m, 64);
    sum3 += __shfl_xor(sum3, m, 64);
  }
  if (l15 == 0) {
    sRed[(row0 + 0) * 2 + wc] = sum0;
    sRed[(row0 + 1) * 2 + wc] = sum1;
    sRed[(row0 + 2) * 2 + wc] = sum2;
    sRed[(row0 + 3) * 2 + wc] = sum3;
  }
  __syncthreads();
  if (tid < QB) sInv[tid] = 1.0f / (sRed[tid * 2] + sRed[tid * 2 + 1]);
  __syncthreads();
  const float inv0 = sInv[row0 + 0], inv1 = sInv[row0 + 1],
              inv2 = sInv[row0 + 2], inv3 = sInv[row0 + 3];

  // =================== PASS B: attn_p + O ===================
  DMA_K(0, 0); DMA_V(0, 0); DMA_C(0, 0);
  __syncthreads();
  f32x4 o0 = {0,0,0,0}, o1 = {0,0,0,0}, o2 = {0,0,0,0}, o3 = {0,0,0,0};
  for (int kt = 0; kt < NKT; ++kt) {
    const int cur = kt & 1;
    if (kt + 1 < NKT) { DMA_K(cur ^ 1, kt + 1); DMA_V(cur ^ 1, kt + 1); DMA_C(cur ^ 1, kt + 1); }
    f32x4 acc = {0.f, 0.f, 0.f, 0.f};
    bf16x8 bK;
    bK = *(const bf16x8*)&sK[cur][keyloc * DD + ((  0 + l4 * 8) ^ ksw)];
    acc = __builtin_amdgcn_mfma_f32_16x16x32_bf16(qf0, bK, acc, 0, 0, 0);
    bK = *(const bf16x8*)&sK[cur][keyloc * DD + (( 32 + l4 * 8) ^ ksw)];
    acc = __builtin_amdgcn_mfma_f32_16x16x32_bf16(qf1, bK, acc, 0, 0, 0);
    bK = *(const bf16x8*)&sK[cur][keyloc * DD + (( 64 + l4 * 8) ^ ksw)];
    acc = __builtin_amdgcn_mfma_f32_16x16x32_bf16(qf2, bK, acc, 0, 0, 0);
    bK = *(const bf16x8*)&sK[cur][keyloc * DD + (( 96 + l4 * 8) ^ ksw)];
    acc = __builtin_amdgcn_mfma_f32_16x16x32_bf16(qf3, bK, acc, 0, 0, 0);

    const int keyg = kt * KB + keyloc;
    {
      float e0 = __expf(acc[0] * SCALE + sCP[cur][CPIDX(row0 + 0, keyloc)]) * inv0;
      float e1 = __expf(acc[1] * SCALE + sCP[cur][CPIDX(row0 + 1, keyloc)]) * inv1;
      float e2 = __expf(acc[2] * SCALE + sCP[cur][CPIDX(row0 + 2, keyloc)]) * inv2;
      float e3 = __expf(acc[3] * SCALE + sCP[cur][CPIDX(row0 + 3, keyloc)]) * inv3;
      oP[(size_t)(row0 + 0) * LL + keyg] = e0;
      oP[(size_t)(row0 + 1) * LL + keyg] = e1;
      oP[(size_t)(row0 + 2) * LL + keyg] = e2;
      oP[(size_t)(row0 + 3) * LL + keyg] = e3;
      sP[(row0 + 0) * KB + (keyloc ^ (slotRC(row0 + 0) << 3))] = f2bf(e0);
      sP[(row0 + 1) * KB + (keyloc ^ (slotRC(row0 + 1) << 3))] = f2bf(e1);
      sP[(row0 + 2) * KB + (keyloc ^ (slotRC(row0 + 2) << 3))] = f2bf(e2);
      sP[(row0 + 3) * KB + (keyloc ^ (slotRC(row0 + 3) << 3))] = f2bf(e3);
    }
    __syncthreads();   // sP visible (also drains this iter's DMAs early)

    bf16x8 aP = *(const bf16x8*)&sP[qrow * KB + ((l4 * 8) ^ (slotRC(qrow) << 3))];
    bf16x8 bV;
    const int dc = wc * 64 + l15;
    bV = *(const bf16x8*)&sVt[cur][(dc +  0) * KB + ((l4 * 8) ^ (slotRC(dc +  0) << 3))];
    o0 = __builtin_amdgcn_mfma_f32_16x16x32_bf16(aP, bV, o0, 0, 0, 0);
    bV = *(const bf16x8*)&sVt[cur][(dc + 16) * KB + ((l4 * 8) ^ (slotRC(dc + 16) << 3))];
    o1 = __builtin_amdgcn_mfma_f32_16x16x32_bf16(aP, bV, o1, 0, 0, 0);
    bV = *(const bf16x8*)&sVt[cur][(dc + 32) * KB + ((l4 * 8) ^ (slotRC(dc + 32) << 3))];
    o2 = __builtin_amdgcn_mfma_f32_16x16x32_bf16(aP, bV, o2, 0, 0, 0);
    bV = *(const bf16x8*)&sVt[cur][(dc + 48) * KB + ((l4 * 8) ^ (slotRC(dc + 48) << 3))];
    o3 = __builtin_amdgcn_mfma_f32_16x16x32_bf16(aP, bV, o3, 0, 0, 0);
    __syncthreads();
  }

  #pragma unroll
  for (int r = 0; r < 4; ++r) {
    float* dst = oA + (size_t)(row0 + r) * DD + wc * 64 + l15;
    dst[0]  = o0[r];
    dst[16] = o1[r];
    dst[32] = o2[r];
    dst[48] = o3[r];
  }
}

extern "C" void kernel_launch(void* const* d_in, const int* in_sizes, int n_in,
                              void* d_out, int out_size, void* d_ws, size_t ws_size,
                              hipStream_t stream) {
  const float* q = (const float*)d_in[0];
  const float* k = (const float*)d_in[1];
  const float* v = (const float*)d_in[2];
  const int* mask = (const int*)d_in[3];
  const float* probs = (const float*)d_in[4];
  const float* alpha = (const float*)d_in[5];
  float* outA = (float*)d_out;
  float* outP = outA + (size_t)BB * HH * LL * DD;
  unsigned short* kb16 = (unsigned short*)d_ws;
  unsigned short* vt16 = kb16 + (size_t)BB * HH * LL * DD;
  float* cpm = (float*)(vt16 + (size_t)BB * HH * LL * DD);
  hipLaunchKernelGGL(prep_kernel, dim3(BB * HH * 32), dim3(256), 0, stream,
                     k, v, mask, probs, alpha, kb16, vt16, cpm);
  hipLaunchKernelGGL(attn_kernel, dim3(BB * HH * (LL / QB)), dim3(512), 0, stream,
                     q, kb16, vt16, cpm, outA, outP);
}